// Round 6
// baseline (82.156 us; speedup 1.0000x reference)
//
#include <hip/hip_runtime.h>
#include <math.h>

#define D_MODEL 4096
#define NE 64
#define TPB 32                  // tokens per block (one 32x32 MFMA tile)
#define KPW 512                 // k's per wave (8 waves x 512 = 4096)
#define WSTEPS 32               // 512 / 16
#define WS_SHORTS (256 * 2 * 64 * 8)   // 262144 shorts per (hi|lo) region

typedef __attribute__((ext_vector_type(8))) short short8;
typedef __attribute__((ext_vector_type(16))) float f32x16;

__device__ __forceinline__ void split8(const float4& a, const float4& c,
                                       short8& h8, short8& l8) {
    float vv[8] = {a.x, a.y, a.z, a.w, c.x, c.y, c.z, c.w};
#pragma unroll
    for (int j = 0; j < 8; j++) {
        float v = vv[j];
        unsigned u = __float_as_uint(v);
        unsigned r = u + 0x7fffu + ((u >> 16) & 1u);   // bf16 RN (inputs finite)
        float hf = __uint_as_float(r & 0xffff0000u);
        float lo = v - hf;                              // exact
        unsigned u2 = __float_as_uint(lo);
        unsigned r2 = u2 + 0x7fffu + ((u2 >> 16) & 1u);
        h8[j] = (short)(r >> 16);
        l8[j] = (short)(r2 >> 16);
    }
}

// Pre-split W (fp32 [64][4096]) -> ws bf16 hi/lo, fragment-linear:
// hi[((ck*2+nt)*64 + l)*8 + j] = bf16hi(W[nt*32+(l&31)][ck*16+(l>>5)*8+j]), lo at +WS_SHORTS
__global__ void wsplit_kernel(const float* __restrict__ W, short* __restrict__ wsp) {
    const int ck = blockIdx.x;          // 0..255
    const int t  = threadIdx.x;         // 0..127
    const int nt = t >> 6, l = t & 63;
    const int e  = nt * 32 + (l & 31);
    const int k  = ck * 16 + (l >> 5) * 8;
    const float* wp = W + (size_t)e * D_MODEL + k;
    float4 a = *(const float4*)wp, c = *(const float4*)(wp + 4);
    short8 h8, l8;
    split8(a, c, h8, l8);
    const size_t off = ((size_t)(ck * 2 + nt) * 64 + l) * 8;
    *(short8*)(wsp + off)             = h8;
    *(short8*)(wsp + WS_SHORTS + off) = l8;
}

template<bool PRE>
__global__ __launch_bounds__(512, 4) void router_kernel(
    const float* __restrict__ x, const float* __restrict__ W,
    const short* __restrict__ wsp, const float* __restrict__ b,
    float* __restrict__ out, int T)
{
    __shared__ short smem[16384];   // 32 KB: reduction slabs / logits (epilogue only)

    const int tid  = threadIdx.x;
    const int wv   = __builtin_amdgcn_readfirstlane(tid >> 6); // 0..7 = K-region
    const int lane = tid & 63;
    const int tok0 = blockIdx.x * TPB;

    const int row = lane & 31;        // token-in-tile (A) / expert-in-group (B)
    const int kh  = lane >> 5;        // k-half of the 16-k step

    // this wave's x fragment stream: 32 B/lane/step, contiguous k
    const float* gx = x + (size_t)(tok0 + row) * D_MODEL + wv * KPW + kh * 8;

    f32x16 acc[2];
#pragma unroll
    for (int e = 0; e < 16; e++) { acc[0][e] = 0.f; acc[1][e] = 0.f; }

    // ---- prologue: load step 0 (x fp32 + W frags), no LDS, no barriers
    float4 xa, xb;
    short8 B0h, B0l, B1h, B1l;
    {
        xa = *(const float4*)gx;
        xb = *(const float4*)(gx + 4);
        if (PRE) {
            const size_t ck = (size_t)(wv * WSTEPS);
            B0h = *(const short8*)(wsp + ((ck * 2 + 0) * 64 + lane) * 8);
            B1h = *(const short8*)(wsp + ((ck * 2 + 1) * 64 + lane) * 8);
            B0l = *(const short8*)(wsp + WS_SHORTS + ((ck * 2 + 0) * 64 + lane) * 8);
            B1l = *(const short8*)(wsp + WS_SHORTS + ((ck * 2 + 1) * 64 + lane) * 8);
        } else {
            const int k0 = wv * KPW + kh * 8;
            const float* w0 = W + (size_t)row * D_MODEL + k0;
            const float* w1 = W + (size_t)(32 + row) * D_MODEL + k0;
            split8(*(const float4*)w0, *(const float4*)(w0 + 4), B0h, B0l);
            split8(*(const float4*)w1, *(const float4*)(w1 + 4), B1h, B1l);
        }
    }

    for (int s = 0; s < WSTEPS; s++) {
        const bool more = (s + 1 < WSTEPS);
        float4 nxa, nxb, nw00, nw01, nw10, nw11;
        short8 nB0h, nB0l, nB1h, nB1l;
        if (more) {   // distance-1 register prefetch; compiler pipelines freely
            const float* g = gx + (size_t)(s + 1) * 16;
            nxa = *(const float4*)g;
            nxb = *(const float4*)(g + 4);
            if (PRE) {
                const size_t ck = (size_t)(wv * WSTEPS + s + 1);
                nB0h = *(const short8*)(wsp + ((ck * 2 + 0) * 64 + lane) * 8);
                nB1h = *(const short8*)(wsp + ((ck * 2 + 1) * 64 + lane) * 8);
                nB0l = *(const short8*)(wsp + WS_SHORTS + ((ck * 2 + 0) * 64 + lane) * 8);
                nB1l = *(const short8*)(wsp + WS_SHORTS + ((ck * 2 + 1) * 64 + lane) * 8);
            } else {
                const int k0 = wv * KPW + (s + 1) * 16 + kh * 8;
                const float* w0 = W + (size_t)row * D_MODEL + k0;
                const float* w1 = W + (size_t)(32 + row) * D_MODEL + k0;
                nw00 = *(const float4*)w0; nw01 = *(const float4*)(w0 + 4);
                nw10 = *(const float4*)w1; nw11 = *(const float4*)(w1 + 4);
            }
        }
        short8 Ah, Al;
        split8(xa, xb, Ah, Al);
        acc[0] = __builtin_amdgcn_mfma_f32_32x32x16_bf16(Ah, B0h, acc[0], 0, 0, 0);
        acc[0] = __builtin_amdgcn_mfma_f32_32x32x16_bf16(Ah, B0l, acc[0], 0, 0, 0);
        acc[0] = __builtin_amdgcn_mfma_f32_32x32x16_bf16(Al, B0h, acc[0], 0, 0, 0);
        acc[0] = __builtin_amdgcn_mfma_f32_32x32x16_bf16(Al, B0l, acc[0], 0, 0, 0);
        acc[1] = __builtin_amdgcn_mfma_f32_32x32x16_bf16(Ah, B1h, acc[1], 0, 0, 0);
        acc[1] = __builtin_amdgcn_mfma_f32_32x32x16_bf16(Ah, B1l, acc[1], 0, 0, 0);
        acc[1] = __builtin_amdgcn_mfma_f32_32x32x16_bf16(Al, B1h, acc[1], 0, 0, 0);
        acc[1] = __builtin_amdgcn_mfma_f32_32x32x16_bf16(Al, B1l, acc[1], 0, 0, 0);
        if (more) {
            xa = nxa; xb = nxb;
            if (PRE) { B0h = nB0h; B0l = nB0l; B1h = nB1h; B1l = nB1l; }
            else {
                split8(nw00, nw01, B0h, B0l);
                split8(nw10, nw11, B1h, B1l);
            }
        }
    }

    // ---- single sync point: 3-round tree reduction over the 8 K-region waves
    float* red = (float*)smem;
    auto store_slab = [&](int slab) {
        float* sl = red + ((size_t)slab * 64 + lane) * 32;
#pragma unroll
        for (int q = 0; q < 8; q++) {   // quad q -> rotated slot (conflict-dodge)
            const int nt = q >> 2, rg = (q & 3) * 4;
            *(float4*)(sl + ((q + lane) & 7) * 4) =
                make_float4(acc[nt][rg], acc[nt][rg+1], acc[nt][rg+2], acc[nt][rg+3]);
        }
    };
    auto add_slab = [&](int slab) {
        const float* sl = red + ((size_t)slab * 64 + lane) * 32;
#pragma unroll
        for (int q = 0; q < 8; q++) {
            const int nt = q >> 2, rg = (q & 3) * 4;
            float4 v = *(const float4*)(sl + ((q + lane) & 7) * 4);
            acc[nt][rg] += v.x; acc[nt][rg+1] += v.y;
            acc[nt][rg+2] += v.z; acc[nt][rg+3] += v.w;
        }
    };
    __syncthreads();
    if (wv >= 4) store_slab(wv - 4);
    __syncthreads();
    if (wv < 4) add_slab(wv);
    __syncthreads();
    if (wv == 2 || wv == 3) store_slab(wv - 2);
    __syncthreads();
    if (wv < 2) add_slab(wv);
    __syncthreads();
    if (wv == 1) store_slab(0);
    __syncthreads();
    if (wv == 0) add_slab(0);
    __syncthreads();

    // ---- wave 0: logits(+bias) -> LDS [32 tok][68]
    float* lg = (float*)smem;
    if (wv == 0) {
        const int h = lane >> 5, c31 = lane & 31;
        const float bb0 = b[c31], bb1 = b[32 + c31];
#pragma unroll
        for (int nt = 0; nt < 2; nt++) {
#pragma unroll
            for (int e = 0; e < 16; e++) {
                const int r2 = (e & 3) + 8 * (e >> 2) + 4 * h;  // token in tile
                lg[r2 * 68 + nt * 32 + c31] = acc[nt][e] + (nt ? bb1 : bb0);
            }
        }
    }
    __syncthreads();

    // ---- top-2 + softmax + store (thread t = token)
    if (tid < TPB) {
        const float4* rowp = (const float4*)(lg + tid * 68);
        float v0 = -INFINITY, v1 = -INFINITY;
        int i0 = 0, i1 = 0;
#pragma unroll
        for (int q = 0; q < 16; q++) {
            float4 v4 = rowp[q];
            float vs[4] = {v4.x, v4.y, v4.z, v4.w};
#pragma unroll
            for (int j = 0; j < 4; j++) {
                const int e = q * 4 + j;
                const float v = vs[j];
                if (v > v0)      { v1 = v0; i1 = i0; v0 = v; i0 = e; }
                else if (v > v1) { v1 = v;  i1 = e; }
            }
        }
        const float e1 = expf(v1 - v0);     // v0 >= v1
        const float w0 = 1.f / (1.f + e1);
        const int tok = tok0 + tid;
        out[tok * 2 + 0] = w0;
        out[tok * 2 + 1] = e1 * w0;
        float* oi = out + (size_t)T * 2;    // indices chunk (float-cast)
        oi[tok * 2 + 0] = (float)i0;
        oi[tok * 2 + 1] = (float)i1;
    }
}

extern "C" void kernel_launch(void* const* d_in, const int* in_sizes, int n_in,
                              void* d_out, int out_size, void* d_ws, size_t ws_size,
                              hipStream_t stream) {
    const float* x = (const float*)d_in[0];
    const float* W = (const float*)d_in[1];
    const float* b = (const float*)d_in[2];
    float* out = (float*)d_out;
    short* wsp = (short*)d_ws;
    const int T = in_sizes[0] / D_MODEL;     // 16384 tokens
    const int grid = T / TPB;                // 512 blocks -> 2 per CU

    const bool pre = (ws_size >= (size_t)(2 * WS_SHORTS) * sizeof(short));  // 1 MB
    if (pre) {
        hipLaunchKernelGGL(wsplit_kernel, dim3(256), dim3(128), 0, stream, W, wsp);
        hipLaunchKernelGGL((router_kernel<true>), dim3(grid), dim3(512), 0, stream,
                           x, W, wsp, b, out, T);
    } else {
        hipLaunchKernelGGL((router_kernel<false>), dim3(grid), dim3(512), 0, stream,
                           x, W, wsp, b, out, T);
    }
}